// Round 1
// baseline (511.500 us; speedup 1.0000x reference)
//
#include <hip/hip_runtime.h>
#include <math.h>

#define TT 2048
#define DMODEL 512
#define NHEADS 8
#define DHEAD 64
#define NBATCH 2
#define MTOK (NBATCH*TT)

typedef unsigned short u16;
typedef unsigned int u32;
typedef __bf16 bf16x8 __attribute__((ext_vector_type(8)));
typedef float f32x4 __attribute__((ext_vector_type(4)));

#define MFMA16(a,b,c) __builtin_amdgcn_mfma_f32_16x16x32_bf16(a,b,c,0,0,0)

__device__ __forceinline__ u16 f2b(float f){
  u32 x = __float_as_uint(f);
  x = x + 0x7fffu + ((x >> 16) & 1u);
  return (u16)(x >> 16);
}
__device__ __forceinline__ float b2f(u16 u){
  return __uint_as_float(((u32)u) << 16);
}

// ---------------- weight prep: ws = mean|W| + 1e-5, ternary Wt ----------------
__global__ __launch_bounds__(256) void wprep1_kernel(
    const float* __restrict__ W0, const float* __restrict__ W1,
    const float* __restrict__ W2, const float* __restrict__ W3,
    const float* __restrict__ W4, float* __restrict__ partial)
{
  int widx = blockIdx.y;
  const float* W = (widx==0)?W0:(widx==1)?W1:(widx==2)?W2:(widx==3)?W3:W4;
  size_t base = (size_t)blockIdx.x * 4096;
  int tid = threadIdx.x;
  float s = 0.f;
  for (int i = tid; i < 4096; i += 256) s += fabsf(W[base + i]);
  __shared__ float red[256];
  red[tid] = s; __syncthreads();
  for (int o = 128; o > 0; o >>= 1){ if (tid < o) red[tid] += red[tid+o]; __syncthreads(); }
  if (tid == 0) partial[widx*64 + blockIdx.x] = red[0];
}

__global__ __launch_bounds__(256) void wprep2_kernel(
    const float* __restrict__ W0, const float* __restrict__ W1,
    const float* __restrict__ W2, const float* __restrict__ W3,
    const float* __restrict__ W4, const float* __restrict__ partial,
    float* __restrict__ wsv, u16* __restrict__ wt)
{
  int widx = blockIdx.y;
  const float* W = (widx==0)?W0:(widx==1)?W1:(widx==2)?W2:(widx==3)?W3:W4;
  __shared__ float red[64];
  int tid = threadIdx.x;
  if (tid < 64) red[tid] = partial[widx*64 + tid];
  __syncthreads();
  for (int o = 32; o > 0; o >>= 1){ if (tid < o) red[tid] += red[tid+o]; __syncthreads(); }
  float ws = red[0] * (1.0f/262144.0f) + 1e-5f;
  if (blockIdx.x == 0 && tid == 0) wsv[widx] = ws;
  size_t base = (size_t)blockIdx.x * 1024;
  for (int i = tid; i < 1024; i += 256){
    float v = rintf(W[base + i] / ws);
    v = fminf(fmaxf(v, -1.f), 1.f);
    wt[(size_t)widx*262144 + base + i] = f2b(v);
  }
}

// ---------------- LayerNorm + activation quant (per token) ----------------
__global__ __launch_bounds__(256) void lnq_kernel(
    const float* __restrict__ x, const float* __restrict__ g, const float* __restrict__ b,
    const int* __restrict__ bwp, u16* __restrict__ xq, float* __restrict__ stok)
{
  int t = blockIdx.x;
  const float* xr = x + (size_t)t * DMODEL;
  int tid = threadIdx.x;
  float v0 = xr[tid], v1 = xr[tid + 256];
  __shared__ float red[256];
  red[tid] = v0 + v1; __syncthreads();
  for (int o=128;o>0;o>>=1){ if(tid<o) red[tid]+=red[tid+o]; __syncthreads(); }
  float mu = red[0] * (1.0f/512.0f);
  __syncthreads();
  float d0 = v0 - mu, d1 = v1 - mu;
  red[tid] = d0*d0 + d1*d1; __syncthreads();
  for (int o=128;o>0;o>>=1){ if(tid<o) red[tid]+=red[tid+o]; __syncthreads(); }
  float var = red[0] * (1.0f/512.0f);
  __syncthreads();
  float rs = rsqrtf(var + 1e-5f);
  float y0 = d0*rs*g[tid] + b[tid];
  float y1 = d1*rs*g[tid+256] + b[tid+256];
  red[tid] = fmaxf(fabsf(y0), fabsf(y1)); __syncthreads();
  for (int o=128;o>0;o>>=1){ if(tid<o) red[tid]=fmaxf(red[tid],red[tid+o]); __syncthreads(); }
  float amax = red[0];
  float Qb = (float)((1 << (bwp[0]-1)) - 1);
  float xs = Qb / (amax + 1e-5f);
  if (tid == 0) stok[t] = (amax + 1e-5f) / Qb;
  float q0 = fminf(fmaxf(rintf(y0 * xs), -Qb), Qb);
  float q1 = fminf(fmaxf(rintf(y1 * xs), -Qb), Qb);
  xq[(size_t)t*DMODEL + tid]       = f2b(q0);
  xq[(size_t)t*DMODEL + tid + 256] = f2b(q1);
}

// ---------------- activation quant only (per token row of 512 f32) ----------------
__global__ __launch_bounds__(256) void quant_kernel(
    const float* __restrict__ src, const int* __restrict__ bwp,
    u16* __restrict__ xq, float* __restrict__ stok)
{
  int t = blockIdx.x;
  const float* xr = src + (size_t)t * DMODEL;
  int tid = threadIdx.x;
  float v0 = xr[tid], v1 = xr[tid + 256];
  __shared__ float red[256];
  red[tid] = fmaxf(fabsf(v0), fabsf(v1)); __syncthreads();
  for (int o=128;o>0;o>>=1){ if(tid<o) red[tid]=fmaxf(red[tid],red[tid+o]); __syncthreads(); }
  float amax = red[0];
  float Qb = (float)((1 << (bwp[0]-1)) - 1);
  float xs = Qb / (amax + 1e-5f);
  if (tid == 0) stok[t] = (amax + 1e-5f) / Qb;
  float q0 = fminf(fmaxf(rintf(v0 * xs), -Qb), Qb);
  float q1 = fminf(fmaxf(rintf(v1 * xs), -Qb), Qb);
  xq[(size_t)t*DMODEL + tid]       = f2b(q0);
  xq[(size_t)t*DMODEL + tid + 256] = f2b(q1);
}

// ---------------- mask row flags: 1 if whole row nonzero ----------------
__global__ __launch_bounds__(256) void maskflag_kernel(const int* __restrict__ mask, int* __restrict__ rowflag){
  int row = blockIdx.x; // b*TT + q
  int tid = threadIdx.x;
  int ok = 1;
  const int* mr = mask + (size_t)row * TT;
  for (int i = tid; i < TT; i += 256) ok &= (mr[i] != 0);
  __shared__ int red[256];
  red[tid] = ok; __syncthreads();
  for (int o=128;o>0;o>>=1){ if(tid<o) red[tid] &= red[tid+o]; __syncthreads(); }
  if (tid == 0) rowflag[row] = red[0];
}

// ---------------- quantized GEMM: out[m,n] = (sum_k A[m,k]*Wt[n,k]) * ws*stok[m] + bias[n] ----------------
// modes: 0=Q->(Qu,Qv bf16 [bh][t][d]) 1=K->bf16 [bh][t][d] 2=V->bf16 Vt [bh][d][t]
//        3=P->bf16 [h][t][d]          4=O->f32 d_out = x + val*maskrow
__global__ __launch_bounds__(256) void qgemm_kernel(
    const u16* __restrict__ A, const u16* __restrict__ Wt,
    const float* __restrict__ stok, const float* __restrict__ wsv, int widx,
    const float* __restrict__ bias, int mode,
    u16* __restrict__ outA, u16* __restrict__ outB, float* __restrict__ outF,
    const float* __restrict__ pbu, const float* __restrict__ pbv,
    const float* __restrict__ xin, const int* __restrict__ mask)
{
  int w = threadIdx.x >> 6, lane = threadIdx.x & 63;
  int g = lane >> 4, li = lane & 15;
  int mb = blockIdx.y*64 + w*16;
  int nb = blockIdx.x*64;
  f32x4 acc[4] = {{0,0,0,0},{0,0,0,0},{0,0,0,0},{0,0,0,0}};
  const u16* Ar = A + (size_t)(mb + li)*DMODEL;
  for (int k0 = 0; k0 < DMODEL; k0 += 32){
    bf16x8 a = *(const bf16x8*)(Ar + k0 + 8*g);
#pragma unroll
    for (int f = 0; f < 4; f++){
      bf16x8 bb = *(const bf16x8*)(Wt + (size_t)(nb + 16*f + li)*DMODEL + k0 + 8*g);
      acc[f] = MFMA16(a, bb, acc[f]);
    }
  }
  float ws = wsv[widx];
  float sc[4];
#pragma unroll
  for (int r=0;r<4;r++) sc[r] = ws * stok[mb + 4*g + r];
#pragma unroll
  for (int f=0;f<4;f++){
    int n = nb + 16*f + li;
    float bn = bias[n];
#pragma unroll
    for (int r=0;r<4;r++){
      int m = mb + 4*g + r;
      float val = acc[f][r]*sc[r] + bn;
      if (mode == 0){
        int bb_ = m >> 11, t = m & (TT-1); int h = n >> 6, d = n & 63;
        size_t o = (((size_t)(bb_*NHEADS + h))*TT + t)*DHEAD + d;
        outA[o] = f2b(val + pbu[n]);
        outB[o] = f2b(val + pbv[n]);
      } else if (mode == 1){
        int bb_ = m >> 11, t = m & (TT-1); int h = n >> 6, d = n & 63;
        size_t o = (((size_t)(bb_*NHEADS + h))*TT + t)*DHEAD + d;
        outA[o] = f2b(val);
      } else if (mode == 2){
        int bb_ = m >> 11, t = m & (TT-1); int h = n >> 6, d = n & 63;
        size_t o = (((size_t)(bb_*NHEADS + h))*DHEAD + d)*TT + t;
        outA[o] = f2b(val);
      } else if (mode == 3){
        int h = n >> 6, d = n & 63;
        size_t o = ((size_t)h*TT + m)*DHEAD + d;
        outA[o] = f2b(val);
      } else {
        int bb_ = m >> 11, t = m & (TT-1);
        float mv = (float)mask[((size_t)bb_*TT + t)*TT];
        outF[(size_t)m*DMODEL + n] = xin[(size_t)m*DMODEL + n] + val*mv;
      }
    }
  }
}

// ---------------- bd GEMM with rel_shift folded into the store ----------------
// R[q,j] = Qv[q]·p[j];  R[q,j] -> bd_s[q][j-(TT-1)+q] if j>=TT-1-q
//                       R[q,j] -> bd_s[q-1][q+j+1]   if q>=1 && j<=TT-2-q
// bd_s[q][q+1] is never written (it is exactly zero; flash substitutes 0).
__global__ __launch_bounds__(256) void bd_kernel(
    const u16* __restrict__ Qv, const u16* __restrict__ Pb, u16* __restrict__ bds)
{
  int w = threadIdx.x >> 6, lane = threadIdx.x & 63;
  int g = lane >> 4, li = lane & 15;
  int bh = blockIdx.z; int h = bh & 7;
  int qb = blockIdx.y*64 + w*16;
  int jb = blockIdx.x*64;
  const u16* qrow = Qv + ((size_t)bh*TT + qb + li)*DHEAD;
  bf16x8 a0 = *(const bf16x8*)(qrow + 8*g);
  bf16x8 a1 = *(const bf16x8*)(qrow + 32 + 8*g);
  size_t base = (size_t)bh*TT*TT;
#pragma unroll
  for (int f = 0; f < 4; f++){
    int jc = jb + 16*f + li;
    const u16* prow = Pb + ((size_t)h*TT + jc)*DHEAD;
    bf16x8 b0 = *(const bf16x8*)(prow + 8*g);
    bf16x8 b1 = *(const bf16x8*)(prow + 32 + 8*g);
    f32x4 c = {0,0,0,0};
    c = MFMA16(a0, b0, c);
    c = MFMA16(a1, b1, c);
#pragma unroll
    for (int r = 0; r < 4; r++){
      int q = qb + 4*g + r;
      u16 vb = f2b(c[r]);
      if (jc >= TT-1-q)               bds[base + (size_t)q*TT + (jc - (TT-1) + q)] = vb;
      if (q >= 1 && jc <= TT-2-q)     bds[base + (size_t)(q-1)*TT + (q + jc + 1)] = vb;
    }
  }
}

// ---------------- flash attention: scores = (QuK^T + bd_s)*0.125, online softmax, @V ----------------
__global__ __launch_bounds__(256) void flash_kernel(
    const u16* __restrict__ Qu, const u16* __restrict__ Kb,
    const u16* __restrict__ Vt, const u16* __restrict__ bds,
    const int* __restrict__ mask, const int* __restrict__ rowflag,
    float* __restrict__ Hout)
{
  int w = threadIdx.x >> 6, lane = threadIdx.x & 63;
  int g = lane >> 4, li = lane & 15;
  int bh = blockIdx.y; int b = bh >> 3, h = bh & 7;
  int qb = blockIdx.x*64 + w*16;
  __shared__ u16 plds[4][16][32];

  const u16* qrow = Qu + ((size_t)bh*TT + qb + li)*DHEAD;
  bf16x8 qu0 = *(const bf16x8*)(qrow + 8*g);
  bf16x8 qu1 = *(const bf16x8*)(qrow + 32 + 8*g);

  f32x4 acc0 = {0,0,0,0}, acc1 = {0,0,0,0}, acc2 = {0,0,0,0}, acc3 = {0,0,0,0};
  float mrun[4] = {-INFINITY,-INFINITY,-INFINITY,-INFINITY};
  float lrun[4] = {0,0,0,0};
  int qrow4[4]; int rf[4];
#pragma unroll
  for (int r=0;r<4;r++){ qrow4[r] = qb + 4*g + r; rf[r] = rowflag[b*TT + qrow4[r]]; }
  const size_t bdbase = (size_t)bh*TT*TT;
  const int* maskb = mask + (size_t)b*TT*TT;

  for (int k0 = 0; k0 < TT; k0 += 32){
    f32x4 s0 = {0,0,0,0}, s1 = {0,0,0,0};
    {
      const u16* kr = Kb + ((size_t)bh*TT + k0 + li)*DHEAD;
      bf16x8 k00 = *(const bf16x8*)(kr + 8*g);
      bf16x8 k01 = *(const bf16x8*)(kr + 32 + 8*g);
      s0 = MFMA16(qu0, k00, s0); s0 = MFMA16(qu1, k01, s0);
      const u16* kr1 = kr + 16*DHEAD;
      bf16x8 k10 = *(const bf16x8*)(kr1 + 8*g);
      bf16x8 k11 = *(const bf16x8*)(kr1 + 32 + 8*g);
      s1 = MFMA16(qu0, k10, s1); s1 = MFMA16(qu1, k11, s1);
    }
    int ka = k0 + li, kb2 = k0 + 16 + li;
#pragma unroll
    for (int r=0;r<4;r++){
      int q = qrow4[r];
      float bd0 = (ka  == q+1) ? 0.f : b2f(bds[bdbase + (size_t)q*TT + ka]);
      float bd1 = (kb2 == q+1) ? 0.f : b2f(bds[bdbase + (size_t)q*TT + kb2]);
      float sv0 = (s0[r] + bd0) * 0.125f;
      float sv1 = (s1[r] + bd1) * 0.125f;
      if (!rf[r]){
        if (maskb[(size_t)q*TT + ka]  == 0) sv0 = -INFINITY;
        if (maskb[(size_t)q*TT + kb2] == 0) sv1 = -INFINITY;
      }
      float tm = fmaxf(sv0, sv1);
#pragma unroll
      for (int o=1;o<16;o<<=1) tm = fmaxf(tm, __shfl_xor(tm, o));
      float mn = fmaxf(mrun[r], tm);
      float fsc = (mrun[r] == -INFINITY) ? 0.f : expf(mrun[r] - mn);
      float p0 = (sv0 == -INFINITY) ? 0.f : expf(sv0 - mn);
      float p1 = (sv1 == -INFINITY) ? 0.f : expf(sv1 - mn);
      float ps = p0 + p1;
#pragma unroll
      for (int o=1;o<16;o<<=1) ps += __shfl_xor(ps, o);
      lrun[r] = lrun[r]*fsc + ps;
      mrun[r] = mn;
      acc0[r]*=fsc; acc1[r]*=fsc; acc2[r]*=fsc; acc3[r]*=fsc;
      plds[w][4*g+r][li]      = f2b(p0);
      plds[w][4*g+r][16+li]   = f2b(p1);
    }
    __syncthreads();
    bf16x8 pa = *(const bf16x8*)(&plds[w][li][8*g]);
    {
      const u16* vb = Vt + ((size_t)bh*DHEAD + li)*TT + k0 + 8*g;
      acc0 = MFMA16(pa, *(const bf16x8*)(vb),                      acc0);
      acc1 = MFMA16(pa, *(const bf16x8*)(vb + (size_t)16*TT),      acc1);
      acc2 = MFMA16(pa, *(const bf16x8*)(vb + (size_t)32*TT),      acc2);
      acc3 = MFMA16(pa, *(const bf16x8*)(vb + (size_t)48*TT),      acc3);
    }
    __syncthreads();
  }
#pragma unroll
  for (int r=0;r<4;r++){
    float inv = (lrun[r] > 0.f) ? 1.0f/lrun[r] : 0.f;
    size_t o = ((size_t)(b*TT + qrow4[r]))*DMODEL + h*DHEAD + li;
    Hout[o]      = acc0[r]*inv;
    Hout[o + 16] = acc1[r]*inv;
    Hout[o + 32] = acc2[r]*inv;
    Hout[o + 48] = acc3[r]*inv;
  }
}

// ---------------- launch ----------------
extern "C" void kernel_launch(void* const* d_in, const int* in_sizes, int n_in,
                              void* d_out, int out_size, void* d_ws, size_t ws_size,
                              hipStream_t stream) {
  const float* x    = (const float*)d_in[0];
  const int*   mask = (const int*)  d_in[1];
  const float* pos  = (const float*)d_in[2];
  const float* lng  = (const float*)d_in[3];
  const float* lnb  = (const float*)d_in[4];
  const float* Wq   = (const float*)d_in[5];
  const float* bq   = (const float*)d_in[6];
  const float* Wk   = (const float*)d_in[7];
  const float* bk   = (const float*)d_in[8];
  const float* Wv   = (const float*)d_in[9];
  const float* bv   = (const float*)d_in[10];
  const float* Wp   = (const float*)d_in[11];
  const float* bp   = (const float*)d_in[12];
  const float* Wo   = (const float*)d_in[13];
  const float* bo   = (const float*)d_in[14];
  const float* pbu  = (const float*)d_in[15];
  const float* pbv  = (const float*)d_in[16];
  const int*   bwp  = (const int*)  d_in[17];
  float* out = (float*)d_out;

  char* wsb = (char*)d_ws;
  size_t off = 0;
  auto alloc = [&](size_t nbytes)->char* {
    char* p = wsb + off;
    off = (off + nbytes + 255) & ~(size_t)255;
    return p;
  };
  float* partial = (float*)alloc(5*64*sizeof(float));
  float* wsv     = (float*)alloc(5*sizeof(float));
  u16*   wt      = (u16*)  alloc((size_t)5*262144*2);
  u16*   xq_y    = (u16*)  alloc((size_t)MTOK*DMODEL*2);
  float* stok_y  = (float*)alloc(MTOK*sizeof(float));
  u16*   xq_p    = (u16*)  alloc((size_t)TT*DMODEL*2);
  float* stok_p  = (float*)alloc(TT*sizeof(float));
  u16*   Qu      = (u16*)  alloc((size_t)16*TT*DHEAD*2);
  u16*   Qv      = (u16*)  alloc((size_t)16*TT*DHEAD*2);
  u16*   Kb      = (u16*)  alloc((size_t)16*TT*DHEAD*2);
  u16*   Vt      = (u16*)  alloc((size_t)16*TT*DHEAD*2);
  u16*   Pb      = (u16*)  alloc((size_t)NHEADS*TT*DHEAD*2);
  float* Hf      = (float*)alloc((size_t)MTOK*DMODEL*sizeof(float));
  u16*   xq_H    = (u16*)  alloc((size_t)MTOK*DMODEL*2);
  float* stok_H  = (float*)alloc(MTOK*sizeof(float));
  int*   rowflag = (int*)  alloc(MTOK*sizeof(int));
  u16*   bds     = (u16*)  alloc((size_t)16*TT*TT*2);
  if (off > ws_size) return;  // clean fail if workspace too small

  // weight prep
  wprep1_kernel<<<dim3(64,5), 256, 0, stream>>>(Wq, Wk, Wv, Wp, Wo, partial);
  wprep2_kernel<<<dim3(256,5), 256, 0, stream>>>(Wq, Wk, Wv, Wp, Wo, partial, wsv, wt);
  // activations
  lnq_kernel<<<MTOK, 256, 0, stream>>>(x, lng, lnb, bwp, xq_y, stok_y);
  quant_kernel<<<TT, 256, 0, stream>>>(pos, bwp, xq_p, stok_p);
  maskflag_kernel<<<MTOK, 256, 0, stream>>>(mask, rowflag);
  // projections
  qgemm_kernel<<<dim3(8,64), 256, 0, stream>>>(xq_y, wt + (size_t)0*262144, stok_y, wsv, 0, bq, 0,
                                               Qu, Qv, nullptr, pbu, pbv, nullptr, nullptr);
  qgemm_kernel<<<dim3(8,64), 256, 0, stream>>>(xq_y, wt + (size_t)1*262144, stok_y, wsv, 1, bk, 1,
                                               Kb, nullptr, nullptr, nullptr, nullptr, nullptr, nullptr);
  qgemm_kernel<<<dim3(8,64), 256, 0, stream>>>(xq_y, wt + (size_t)2*262144, stok_y, wsv, 2, bv, 2,
                                               Vt, nullptr, nullptr, nullptr, nullptr, nullptr, nullptr);
  qgemm_kernel<<<dim3(8,32), 256, 0, stream>>>(xq_p, wt + (size_t)3*262144, stok_p, wsv, 3, bp, 3,
                                               Pb, nullptr, nullptr, nullptr, nullptr, nullptr, nullptr);
  // rel-pos matrix (shift folded into stores)
  bd_kernel<<<dim3(32,32,16), 256, 0, stream>>>(Qv, Pb, bds);
  // fused attention
  flash_kernel<<<dim3(32,16), 256, 0, stream>>>(Qu, Kb, Vt, bds, mask, rowflag, Hf);
  // output projection (+ residual + seq mask)
  quant_kernel<<<MTOK, 256, 0, stream>>>(Hf, bwp, xq_H, stok_H);
  qgemm_kernel<<<dim3(8,64), 256, 0, stream>>>(xq_H, wt + (size_t)4*262144, stok_H, wsv, 4, bo, 4,
                                               nullptr, nullptr, out, nullptr, nullptr, x, mask);
}

// Round 2
// 462.759 us; speedup vs baseline: 1.1053x; 1.1053x over previous
//
#include <hip/hip_runtime.h>
#include <math.h>

#define TT 2048
#define DMODEL 512
#define NHEADS 8
#define DHEAD 64
#define NBATCH 2
#define MTOK (NBATCH*TT)

typedef unsigned short u16;
typedef unsigned int u32;
typedef __bf16 bf16x8 __attribute__((ext_vector_type(8)));
typedef float f32x4 __attribute__((ext_vector_type(4)));
typedef short s16x4 __attribute__((ext_vector_type(4)));
typedef unsigned short u16x4 __attribute__((ext_vector_type(4)));

#define MFMA16(a,b,c) __builtin_amdgcn_mfma_f32_16x16x32_bf16(a,b,c,0,0,0)
#define MFMA_PV(a,b,c) __builtin_amdgcn_mfma_f32_16x16x16bf16_1k(a,b,c,0,0,0)

__device__ __forceinline__ u16 f2b(float f){
  u32 x = __float_as_uint(f);
  x = x + 0x7fffu + ((x >> 16) & 1u);
  return (u16)(x >> 16);
}
__device__ __forceinline__ float b2f(u16 u){
  return __uint_as_float(((u32)u) << 16);
}

// ---------------- weight prep: ws = mean|W| + 1e-5, ternary Wt ----------------
__global__ __launch_bounds__(256) void wprep1_kernel(
    const float* __restrict__ W0, const float* __restrict__ W1,
    const float* __restrict__ W2, const float* __restrict__ W3,
    const float* __restrict__ W4, float* __restrict__ partial)
{
  int widx = blockIdx.y;
  const float* W = (widx==0)?W0:(widx==1)?W1:(widx==2)?W2:(widx==3)?W3:W4;
  size_t base = (size_t)blockIdx.x * 4096;
  int tid = threadIdx.x;
  float s = 0.f;
  for (int i = tid; i < 4096; i += 256) s += fabsf(W[base + i]);
  __shared__ float red[256];
  red[tid] = s; __syncthreads();
  for (int o = 128; o > 0; o >>= 1){ if (tid < o) red[tid] += red[tid+o]; __syncthreads(); }
  if (tid == 0) partial[widx*64 + blockIdx.x] = red[0];
}

__global__ __launch_bounds__(256) void wprep2_kernel(
    const float* __restrict__ W0, const float* __restrict__ W1,
    const float* __restrict__ W2, const float* __restrict__ W3,
    const float* __restrict__ W4, const float* __restrict__ partial,
    float* __restrict__ wsv, u16* __restrict__ wt)
{
  int widx = blockIdx.y;
  const float* W = (widx==0)?W0:(widx==1)?W1:(widx==2)?W2:(widx==3)?W3:W4;
  __shared__ float red[64];
  int tid = threadIdx.x;
  if (tid < 64) red[tid] = partial[widx*64 + tid];
  __syncthreads();
  for (int o = 32; o > 0; o >>= 1){ if (tid < o) red[tid] += red[tid+o]; __syncthreads(); }
  float ws = red[0] * (1.0f/262144.0f) + 1e-5f;
  if (blockIdx.x == 0 && tid == 0) wsv[widx] = ws;
  size_t base = (size_t)blockIdx.x * 1024;
  for (int i = tid; i < 1024; i += 256){
    float v = rintf(W[base + i] / ws);
    v = fminf(fmaxf(v, -1.f), 1.f);
    wt[(size_t)widx*262144 + base + i] = f2b(v);
  }
}

// ---------------- LayerNorm + activation quant (per token) ----------------
__global__ __launch_bounds__(256) void lnq_kernel(
    const float* __restrict__ x, const float* __restrict__ g, const float* __restrict__ b,
    const int* __restrict__ bwp, u16* __restrict__ xq, float* __restrict__ stok)
{
  int t = blockIdx.x;
  const float* xr = x + (size_t)t * DMODEL;
  int tid = threadIdx.x;
  float v0 = xr[tid], v1 = xr[tid + 256];
  __shared__ float red[256];
  red[tid] = v0 + v1; __syncthreads();
  for (int o=128;o>0;o>>=1){ if(tid<o) red[tid]+=red[tid+o]; __syncthreads(); }
  float mu = red[0] * (1.0f/512.0f);
  __syncthreads();
  float d0 = v0 - mu, d1 = v1 - mu;
  red[tid] = d0*d0 + d1*d1; __syncthreads();
  for (int o=128;o>0;o>>=1){ if(tid<o) red[tid]+=red[tid+o]; __syncthreads(); }
  float var = red[0] * (1.0f/512.0f);
  __syncthreads();
  float rs = rsqrtf(var + 1e-5f);
  float y0 = d0*rs*g[tid] + b[tid];
  float y1 = d1*rs*g[tid+256] + b[tid+256];
  red[tid] = fmaxf(fabsf(y0), fabsf(y1)); __syncthreads();
  for (int o=128;o>0;o>>=1){ if(tid<o) red[tid]=fmaxf(red[tid],red[tid+o]); __syncthreads(); }
  float amax = red[0];
  float Qb = (float)((1 << (bwp[0]-1)) - 1);
  float xs = Qb / (amax + 1e-5f);
  if (tid == 0) stok[t] = (amax + 1e-5f) / Qb;
  float q0 = fminf(fmaxf(rintf(y0 * xs), -Qb), Qb);
  float q1 = fminf(fmaxf(rintf(y1 * xs), -Qb), Qb);
  xq[(size_t)t*DMODEL + tid]       = f2b(q0);
  xq[(size_t)t*DMODEL + tid + 256] = f2b(q1);
}

// ---------------- activation quant only (per token row of 512 f32) ----------------
__global__ __launch_bounds__(256) void quant_kernel(
    const float* __restrict__ src, const int* __restrict__ bwp,
    u16* __restrict__ xq, float* __restrict__ stok)
{
  int t = blockIdx.x;
  const float* xr = src + (size_t)t * DMODEL;
  int tid = threadIdx.x;
  float v0 = xr[tid], v1 = xr[tid + 256];
  __shared__ float red[256];
  red[tid] = fmaxf(fabsf(v0), fabsf(v1)); __syncthreads();
  for (int o=128;o>0;o>>=1){ if(tid<o) red[tid]=fmaxf(red[tid],red[tid+o]); __syncthreads(); }
  float amax = red[0];
  float Qb = (float)((1 << (bwp[0]-1)) - 1);
  float xs = Qb / (amax + 1e-5f);
  if (tid == 0) stok[t] = (amax + 1e-5f) / Qb;
  float q0 = fminf(fmaxf(rintf(v0 * xs), -Qb), Qb);
  float q1 = fminf(fmaxf(rintf(v1 * xs), -Qb), Qb);
  xq[(size_t)t*DMODEL + tid]       = f2b(q0);
  xq[(size_t)t*DMODEL + tid + 256] = f2b(q1);
}

// ---------------- mask row flags: 1 if whole row nonzero ----------------
__global__ __launch_bounds__(256) void maskflag_kernel(const int* __restrict__ mask, int* __restrict__ rowflag){
  int row = blockIdx.x; // b*TT + q
  int tid = threadIdx.x;
  int ok = 1;
  const int* mr = mask + (size_t)row * TT;
  for (int i = tid; i < TT; i += 256) ok &= (mr[i] != 0);
  __shared__ int red[256];
  red[tid] = ok; __syncthreads();
  for (int o=128;o>0;o>>=1){ if(tid<o) red[tid] &= red[tid+o]; __syncthreads(); }
  if (tid == 0) rowflag[row] = red[0];
}

// ---------------- quantized GEMM: out[m,n] = (sum_k A[m,k]*Wt[n,k]) * ws*stok[m] + bias[n] ----------------
// modes: 0=Q->(Qu,Qv bf16 [bh][t][d]) 1=K->bf16 [bh][t][d] 2=V->bf16 Vt [bh][d][t]
//        3=P->bf16 [h][t][d]          4=O->f32 d_out = x + val*maskrow
__global__ __launch_bounds__(256) void qgemm_kernel(
    const u16* __restrict__ A, const u16* __restrict__ Wt,
    const float* __restrict__ stok, const float* __restrict__ wsv, int widx,
    const float* __restrict__ bias, int mode,
    u16* __restrict__ outA, u16* __restrict__ outB, float* __restrict__ outF,
    const float* __restrict__ pbu, const float* __restrict__ pbv,
    const float* __restrict__ xin, const int* __restrict__ mask)
{
  int w = threadIdx.x >> 6, lane = threadIdx.x & 63;
  int g = lane >> 4, li = lane & 15;
  int mb = blockIdx.y*64 + w*16;
  int nb = blockIdx.x*64;
  f32x4 acc[4] = {{0,0,0,0},{0,0,0,0},{0,0,0,0},{0,0,0,0}};
  const u16* Ar = A + (size_t)(mb + li)*DMODEL;
  for (int k0 = 0; k0 < DMODEL; k0 += 32){
    bf16x8 a = *(const bf16x8*)(Ar + k0 + 8*g);
#pragma unroll
    for (int f = 0; f < 4; f++){
      bf16x8 bb = *(const bf16x8*)(Wt + (size_t)(nb + 16*f + li)*DMODEL + k0 + 8*g);
      acc[f] = MFMA16(a, bb, acc[f]);
    }
  }
  float ws = wsv[widx];
  float sc[4];
#pragma unroll
  for (int r=0;r<4;r++) sc[r] = ws * stok[mb + 4*g + r];
#pragma unroll
  for (int f=0;f<4;f++){
    int n = nb + 16*f + li;
    float bn = bias[n];
#pragma unroll
    for (int r=0;r<4;r++){
      int m = mb + 4*g + r;
      float val = acc[f][r]*sc[r] + bn;
      if (mode == 0){
        int bb_ = m >> 11, t = m & (TT-1); int h = n >> 6, d = n & 63;
        size_t o = (((size_t)(bb_*NHEADS + h))*TT + t)*DHEAD + d;
        outA[o] = f2b(val + pbu[n]);
        outB[o] = f2b(val + pbv[n]);
      } else if (mode == 1){
        int bb_ = m >> 11, t = m & (TT-1); int h = n >> 6, d = n & 63;
        size_t o = (((size_t)(bb_*NHEADS + h))*TT + t)*DHEAD + d;
        outA[o] = f2b(val);
      } else if (mode == 2){
        int bb_ = m >> 11, t = m & (TT-1); int h = n >> 6, d = n & 63;
        size_t o = (((size_t)(bb_*NHEADS + h))*DHEAD + d)*TT + t;
        outA[o] = f2b(val);
      } else if (mode == 3){
        int h = n >> 6, d = n & 63;
        size_t o = ((size_t)h*TT + m)*DHEAD + d;
        outA[o] = f2b(val);
      } else {
        int bb_ = m >> 11, t = m & (TT-1);
        float mv = (float)mask[((size_t)bb_*TT + t)*TT];
        outF[(size_t)m*DMODEL + n] = xin[(size_t)m*DMODEL + n] + val*mv;
      }
    }
  }
}

// ---------------- bd GEMM with rel_shift folded into the store ----------------
// R[q,j] = Qv[q]·p[j];  R[q,j] -> bd_s[q][j-(TT-1)+q] if j>=TT-1-q
//                       R[q,j] -> bd_s[q-1][q+j+1]   if q>=1 && j<=TT-2-q
// bd_s[q][q+1] is zero; written explicitly when jc==q.
// Storage layout (for coalesced flash reads): bdsw[bh][k>>2][q][k&3]
__global__ __launch_bounds__(256) void bd_kernel(
    const u16* __restrict__ Qv, const u16* __restrict__ Pb, u16* __restrict__ bdsw)
{
  int w = threadIdx.x >> 6, lane = threadIdx.x & 63;
  int g = lane >> 4, li = lane & 15;
  int bh = blockIdx.z; int h = bh & 7;
  int qb = blockIdx.y*64 + w*16;
  int jb = blockIdx.x*64;
  const u16* qrow = Qv + ((size_t)bh*TT + qb + li)*DHEAD;
  bf16x8 a0 = *(const bf16x8*)(qrow + 8*g);
  bf16x8 a1 = *(const bf16x8*)(qrow + 32 + 8*g);
  u16* base = bdsw + (size_t)bh*(TT/4)*TT*4;
#pragma unroll
  for (int f = 0; f < 4; f++){
    int jc = jb + 16*f + li;
    const u16* prow = Pb + ((size_t)h*TT + jc)*DHEAD;
    f32x4 c = {0,0,0,0};
    c = MFMA16(a0, *(const bf16x8*)(prow + 8*g), c);
    c = MFMA16(a1, *(const bf16x8*)(prow + 32 + 8*g), c);
#pragma unroll
    for (int r = 0; r < 4; r++){
      int q = qb + 4*g + r;
      u16 vb = f2b(c[r]);
      if (jc >= TT-1-q){
        int col = jc - (TT-1) + q;
        base[((size_t)(col>>2)*TT + q)*4 + (col&3)] = vb;
      }
      if (q >= 1 && jc <= TT-2-q){
        int col = q + jc + 1;
        base[((size_t)(col>>2)*TT + (q-1))*4 + (col&3)] = vb;
      }
      if (jc == q && q < TT-1){
        int col = q + 1;
        base[((size_t)(col>>2)*TT + q)*4 + (col&3)] = 0;
      }
    }
  }
}

// ---------------- flash attention, swapped-operand, zero-LDS, zero-barrier ----------------
// QK^T: mfma(A=K, B=Qu) -> lane holds scores for q = qb+w*16+(lane&15), k = k0+16kc+4g+r.
// Softmax fully in-register per lane; cross-k reduce = 2x shfl_xor (16,32).
// PV: mfma_f32_16x16x16bf16_1k(A=P in-reg, B=Vt chunk) -- A layout matches P exactly.
__global__ __launch_bounds__(256) void flash_kernel(
    const u16* __restrict__ Qu, const u16* __restrict__ Kb,
    const u16* __restrict__ Vt, const u16* __restrict__ bdsw,
    const int* __restrict__ mask, const int* __restrict__ rowflag,
    float* __restrict__ Hout)
{
  int w = threadIdx.x >> 6, lane = threadIdx.x & 63;
  int g = lane >> 4, li = lane & 15;
  int bh = blockIdx.y; int b = bh >> 3, h = bh & 7;
  int qb = blockIdx.x*64 + w*16;
  int q = qb + li;

  const u16* qrow = Qu + ((size_t)bh*TT + q)*DHEAD;
  bf16x8 qu0 = *(const bf16x8*)(qrow + 8*g);
  bf16x8 qu1 = *(const bf16x8*)(qrow + 32 + 8*g);

  f32x4 acc[4] = {{0,0,0,0},{0,0,0,0},{0,0,0,0},{0,0,0,0}};
  float mrun = -INFINITY, lrun = 0.f;
  int rf = rowflag[b*TT + q];
  bool needmask = (__all(rf) == 0);

  const u16* Kbase = Kb + (size_t)bh*TT*DHEAD;
  const u16* Vrow  = Vt + ((size_t)bh*DHEAD + li)*TT;
  const u16* bdb   = bdsw + (size_t)bh*(TT/4)*TT*4;
  const int* maskq = mask + ((size_t)b*TT + q)*TT;

  for (int k0 = 0; k0 < TT; k0 += 64){
    f32x4 s[4] = {{0,0,0,0},{0,0,0,0},{0,0,0,0},{0,0,0,0}};
#pragma unroll
    for (int kc = 0; kc < 4; kc++){
      const u16* kr = Kbase + (size_t)(k0 + 16*kc + li)*DHEAD;
      s[kc] = MFMA16(*(const bf16x8*)(kr + 8*g),      qu0, s[kc]);
      s[kc] = MFMA16(*(const bf16x8*)(kr + 32 + 8*g), qu1, s[kc]);
    }
    float sv[4][4];
#pragma unroll
    for (int kc = 0; kc < 4; kc++){
      u16x4 bd4 = *(const u16x4*)(bdb + ((size_t)((k0>>2) + 4*kc + g)*TT + q)*4);
#pragma unroll
      for (int r = 0; r < 4; r++) sv[kc][r] = (s[kc][r] + b2f(bd4[r]))*0.125f;
    }
    if (needmask){
#pragma unroll
      for (int kc = 0; kc < 4; kc++)
#pragma unroll
        for (int r = 0; r < 4; r++)
          if (!rf && maskq[k0 + 16*kc + 4*g + r] == 0) sv[kc][r] = -INFINITY;
    }
    float tm = sv[0][0];
#pragma unroll
    for (int kc = 0; kc < 4; kc++)
#pragma unroll
      for (int r = 0; r < 4; r++) tm = fmaxf(tm, sv[kc][r]);
    tm = fmaxf(tm, __shfl_xor(tm, 16));
    tm = fmaxf(tm, __shfl_xor(tm, 32));
    float mn;
    if (__all(tm <= mrun)){
      mn = mrun;                      // exact defer: fsc would be 1
    } else {
      mn = fmaxf(mrun, tm);
      float fscq = (mrun == -INFINITY) ? 0.f : __expf(mrun - mn);
      mrun = mn;
      lrun *= fscq;
#pragma unroll
      for (int r = 0; r < 4; r++){
        float fr = __shfl(fscq, 4*g + r);
        acc[0][r] *= fr; acc[1][r] *= fr; acc[2][r] *= fr; acc[3][r] *= fr;
      }
    }
    float ps = 0.f;
    s16x4 pk[4];
#pragma unroll
    for (int kc = 0; kc < 4; kc++)
#pragma unroll
      for (int r = 0; r < 4; r++){
        float p;
        if (needmask) p = (sv[kc][r] == -INFINITY) ? 0.f : __expf(sv[kc][r] - mn);
        else          p = __expf(sv[kc][r] - mn);
        ps += p;
        pk[kc][r] = (short)f2b(p);
      }
    ps += __shfl_xor(ps, 16);
    ps += __shfl_xor(ps, 32);
    lrun += ps;
#pragma unroll
    for (int kc = 0; kc < 4; kc++){
      const u16* vp = Vrow + k0 + 16*kc + 4*g;
#pragma unroll
      for (int d = 0; d < 4; d++){
        s16x4 vf = *(const s16x4*)(vp + (size_t)d*16*TT);
        acc[d] = MFMA_PV(pk[kc], vf, acc[d]);
      }
    }
  }
  float rl = (lrun > 0.f) ? 1.0f/lrun : 0.f;
#pragma unroll
  for (int r = 0; r < 4; r++){
    float inv = __shfl(rl, 4*g + r);
    size_t o = ((size_t)(b*TT + qb + 4*g + r))*DMODEL + h*DHEAD + li;
    Hout[o]      = acc[0][r]*inv;
    Hout[o + 16] = acc[1][r]*inv;
    Hout[o + 32] = acc[2][r]*inv;
    Hout[o + 48] = acc[3][r]*inv;
  }
}

// ---------------- launch ----------------
extern "C" void kernel_launch(void* const* d_in, const int* in_sizes, int n_in,
                              void* d_out, int out_size, void* d_ws, size_t ws_size,
                              hipStream_t stream) {
  const float* x    = (const float*)d_in[0];
  const int*   mask = (const int*)  d_in[1];
  const float* pos  = (const float*)d_in[2];
  const float* lng  = (const float*)d_in[3];
  const float* lnb  = (const float*)d_in[4];
  const float* Wq   = (const float*)d_in[5];
  const float* bq   = (const float*)d_in[6];
  const float* Wk   = (const float*)d_in[7];
  const float* bk   = (const float*)d_in[8];
  const float* Wv   = (const float*)d_in[9];
  const float* bv   = (const float*)d_in[10];
  const float* Wp   = (const float*)d_in[11];
  const float* bp   = (const float*)d_in[12];
  const float* Wo   = (const float*)d_in[13];
  const float* bo   = (const float*)d_in[14];
  const float* pbu  = (const float*)d_in[15];
  const float* pbv  = (const float*)d_in[16];
  const int*   bwp  = (const int*)  d_in[17];
  float* out = (float*)d_out;

  char* wsb = (char*)d_ws;
  size_t off = 0;
  auto alloc = [&](size_t nbytes)->char* {
    char* p = wsb + off;
    off = (off + nbytes + 255) & ~(size_t)255;
    return p;
  };
  float* partial = (float*)alloc(5*64*sizeof(float));
  float* wsv     = (float*)alloc(5*sizeof(float));
  u16*   wt      = (u16*)  alloc((size_t)5*262144*2);
  u16*   xq_y    = (u16*)  alloc((size_t)MTOK*DMODEL*2);
  float* stok_y  = (float*)alloc(MTOK*sizeof(float));
  u16*   xq_p    = (u16*)  alloc((size_t)TT*DMODEL*2);
  float* stok_p  = (float*)alloc(TT*sizeof(float));
  u16*   Qu      = (u16*)  alloc((size_t)16*TT*DHEAD*2);
  u16*   Qv      = (u16*)  alloc((size_t)16*TT*DHEAD*2);
  u16*   Kb      = (u16*)  alloc((size_t)16*TT*DHEAD*2);
  u16*   Vt      = (u16*)  alloc((size_t)16*TT*DHEAD*2);
  u16*   Pb      = (u16*)  alloc((size_t)NHEADS*TT*DHEAD*2);
  float* Hf      = (float*)alloc((size_t)MTOK*DMODEL*sizeof(float));
  u16*   xq_H    = (u16*)  alloc((size_t)MTOK*DMODEL*2);
  float* stok_H  = (float*)alloc(MTOK*sizeof(float));
  int*   rowflag = (int*)  alloc(MTOK*sizeof(int));
  u16*   bds     = (u16*)  alloc((size_t)16*TT*TT*2);
  if (off > ws_size) return;  // clean fail if workspace too small

  // weight prep
  wprep1_kernel<<<dim3(64,5), 256, 0, stream>>>(Wq, Wk, Wv, Wp, Wo, partial);
  wprep2_kernel<<<dim3(256,5), 256, 0, stream>>>(Wq, Wk, Wv, Wp, Wo, partial, wsv, wt);
  // activations
  lnq_kernel<<<MTOK, 256, 0, stream>>>(x, lng, lnb, bwp, xq_y, stok_y);
  quant_kernel<<<TT, 256, 0, stream>>>(pos, bwp, xq_p, stok_p);
  maskflag_kernel<<<MTOK, 256, 0, stream>>>(mask, rowflag);
  // projections
  qgemm_kernel<<<dim3(8,64), 256, 0, stream>>>(xq_y, wt + (size_t)0*262144, stok_y, wsv, 0, bq, 0,
                                               Qu, Qv, nullptr, pbu, pbv, nullptr, nullptr);
  qgemm_kernel<<<dim3(8,64), 256, 0, stream>>>(xq_y, wt + (size_t)1*262144, stok_y, wsv, 1, bk, 1,
                                               Kb, nullptr, nullptr, nullptr, nullptr, nullptr, nullptr);
  qgemm_kernel<<<dim3(8,64), 256, 0, stream>>>(xq_y, wt + (size_t)2*262144, stok_y, wsv, 2, bv, 2,
                                               Vt, nullptr, nullptr, nullptr, nullptr, nullptr, nullptr);
  qgemm_kernel<<<dim3(8,32), 256, 0, stream>>>(xq_p, wt + (size_t)3*262144, stok_p, wsv, 3, bp, 3,
                                               Pb, nullptr, nullptr, nullptr, nullptr, nullptr, nullptr);
  // rel-pos matrix (shift folded into stores, flash-friendly layout)
  bd_kernel<<<dim3(32,32,16), 256, 0, stream>>>(Qv, Pb, bds);
  // fused attention
  flash_kernel<<<dim3(32,16), 256, 0, stream>>>(Qu, Kb, Vt, bds, mask, rowflag, Hf);
  // output projection (+ residual + seq mask)
  quant_kernel<<<MTOK, 256, 0, stream>>>(Hf, bwp, xq_H, stok_H);
  qgemm_kernel<<<dim3(8,64), 256, 0, stream>>>(xq_H, wt + (size_t)4*262144, stok_H, wsv, 4, bo, 4,
                                               nullptr, nullptr, out, nullptr, nullptr, x, mask);
}